// Round 9
// baseline (2036.460 us; speedup 1.0000x reference)
//
#include <hip/hip_runtime.h>

#define BB 128
#define TT 2048
#define KK 64

__device__ __forceinline__ float max3f(float a, float b, float c) {
    return fmaxf(fmaxf(a, b), c);   // folds to v_max3_f32
}

__device__ __forceinline__ int find_len(const int* mask, int b, int lane) {
    int len = TT;
#pragma unroll 1
    for (int c = 0; c < TT / 64; ++c) {
        int m = mask[b * TT + c * 64 + lane];
        unsigned long long z = __ballot(m == 0);
        if (z) { len = c * 64 + (__ffsll(z) - 1); break; }
    }
    return len;
}

// ---------- k1: serial forward; max via LDS broadcast + max3 tree;
// ----------     argmax via off-critical-path equality scan ----------
__global__ __launch_bounds__(64) __attribute__((amdgpu_waves_per_eu(1, 1)))
void vit_fwd_bp(const float* __restrict__ em, const int* __restrict__ mask,
                const float* __restrict__ trans, unsigned char* __restrict__ bp,
                int* __restrict__ last_tag)
{
    __shared__ __align__(16) float sv[KK];
    const int b = blockIdx.x;
    const int lane = threadIdx.x;
    const float* emb = em + (size_t)b * TT * KK;
    unsigned char* bpb = bp + (size_t)b * TT * KK;

    float tcol[KK];
#pragma unroll
    for (int i = 0; i < KK; ++i) tcol[i] = trans[i * KK + lane];
#pragma unroll
    for (int i = 0; i < KK; ++i) asm volatile("" : "+v"(tcol[i]));

    const int lenm1 = find_len(mask, b, lane) - 1;

    float score = emb[lane];   // t = 0
    sv[lane] = score;

    // one step: value-max on the critical path, publish early,
    // then equality-scan argmax fills the broadcast-stall bubbles
    auto step = [&](float e, int tu) {
        const float4* svq = (const float4*)sv;
        float c[KK];
#pragma unroll
        for (int g = 0; g < 16; ++g) {
            float4 s4 = svq[g];                  // LDS broadcast read
            c[4*g+0] = s4.x + tcol[4*g+0];
            c[4*g+1] = s4.y + tcol[4*g+1];
            c[4*g+2] = s4.z + tcol[4*g+2];
            c[4*g+3] = s4.w + tcol[4*g+3];
        }
        float m1[22];
#pragma unroll
        for (int g = 0; g < 21; ++g) m1[g] = max3f(c[3*g], c[3*g+1], c[3*g+2]);
        m1[21] = c[63];
        float m2[8];
#pragma unroll
        for (int g = 0; g < 7; ++g) m2[g] = max3f(m1[3*g], m1[3*g+1], m1[3*g+2]);
        m2[7] = m1[21];
        float m3a = max3f(m2[0], m2[1], m2[2]);
        float m3b = max3f(m2[3], m2[4], m2[5]);
        float m3c = fmaxf(m2[6], m2[7]);
        float best = max3f(m3a, m3b, m3c);
        score = best + e;
        sv[lane] = score;                        // publish ASAP (next step's dep)

        // off-path: first-occurrence argmax; best is bitwise one of c[]
        int bpi = 63;
#pragma unroll
        for (int i = KK - 2; i >= 0; --i) bpi = (c[i] == best) ? i : bpi;
        bpb[(size_t)tu * KK + lane] = (unsigned char)bpi;
    };

    float ebuf[4];
#pragma unroll
    for (int k = 0; k < 4; ++k) {
        int tp = 1 + k; if (tp > TT - 1) tp = TT - 1;
        ebuf[k] = emb[tp * KK + lane];
    }

    int t = 1;
#pragma unroll 1
    for (; t + 3 <= lenm1; t += 4) {
#pragma unroll
        for (int u = 0; u < 4; ++u) {
            float e = ebuf[u];
            int tp = t + 4 + u; if (tp > TT - 1) tp = TT - 1;
            ebuf[u] = emb[tp * KK + lane];       // prefetch 4 ahead
            step(e, t + u);
        }
    }
#pragma unroll 1
    for (; t <= lenm1; ++t) {
        float e = emb[t * KK + lane];
        step(e, t);
    }

    // final argmax over score (first occurrence) -> last_tag[b]
    float bv = score; int bi = lane;
#pragma unroll
    for (int off = 32; off; off >>= 1) {
        float ov = __shfl_xor(bv, off, 64);
        int oi = __shfl_xor(bi, off, 64);
        bool take = (ov > bv) || ((ov == bv) && (oi < bi));
        bv = take ? ov : bv;
        bi = take ? oi : bi;
    }
    if (lane == 0) last_tag[b] = bi;
}

// ---------- k2: final tag + chunked backtrack + output ----------
__global__ __launch_bounds__(64)
void vit_bt(const int* __restrict__ mask, const unsigned char* __restrict__ bp,
            const int* __restrict__ last_tag, int* __restrict__ out)
{
    const int b = blockIdx.x;
    const int lane = threadIdx.x;
    const unsigned char* bpb = bp + (size_t)b * TT * KK;
    int* outb = out + (size_t)b * TT;

    const int lenm1 = find_len(mask, b, lane) - 1;
    int tag = last_tag[b];

    // zero-fill output rows beyond the top backtrack chunk
    const int cbase_top = lenm1 & ~63;
#pragma unroll 1
    for (int t0 = cbase_top + 64; t0 < TT; t0 += 64) outb[t0 + lane] = 0;

    // chunked backtrack: 64 bp rows live in 16 VGPRs (4x uint4)
    const int rsub = lane >> 2;
    const int boff = (lane & 3) * 16;
    uint4 cur[4], nxt[4];
#pragma unroll
    for (int q = 0; q < 4; ++q)
        cur[q] = *(const uint4*)(bpb + (size_t)(cbase_top + 16 * q + rsub) * 64 + boff);
#pragma unroll
    for (int q = 0; q < 4; ++q) nxt[q] = cur[q];

    int stage = 0;
#pragma unroll 1
    for (int cbase = cbase_top; cbase >= 0; cbase -= 64) {
        if (cbase >= 64) {
#pragma unroll
            for (int q = 0; q < 4; ++q)
                nxt[q] = *(const uint4*)(bpb + (size_t)(cbase - 64 + 16 * q + rsub) * 64 + boff);
        }
#pragma unroll
        for (int s = 63; s >= 0; --s) {
            const int row = cbase + s;
            if (row <= lenm1) {
                stage = (lane == s) ? tag : stage;
                if (row >= 1) {
                    const int q = s >> 4;
                    const int lanei = ((s & 15) << 2) | (tag >> 4);
                    int w0 = __builtin_amdgcn_readlane((int)cur[q].x, lanei);
                    int w1 = __builtin_amdgcn_readlane((int)cur[q].y, lanei);
                    int w2 = __builtin_amdgcn_readlane((int)cur[q].z, lanei);
                    int w3 = __builtin_amdgcn_readlane((int)cur[q].w, lanei);
                    int a0 = (tag & 4) ? w1 : w0;
                    int a1 = (tag & 4) ? w3 : w2;
                    int word = (tag & 8) ? a1 : a0;
                    tag = (word >> ((tag & 3) * 8)) & 0xFF;
                }
            }
        }
        outb[cbase + lane] = stage;
        stage = 0;
#pragma unroll
        for (int q = 0; q < 4; ++q) cur[q] = nxt[q];
    }
}

// ---------- fallback monolith (if ws too small; needs 16 MiB) ----------
__device__ __forceinline__ float rlane_f(float v, int lane) {
    return __int_as_float(__builtin_amdgcn_readlane(__float_as_int(v), lane));
}

__global__ __launch_bounds__(64) __attribute__((amdgpu_waves_per_eu(1, 1)))
void viterbi64(const float* __restrict__ em, const int* __restrict__ mask,
               const float* __restrict__ trans, int* __restrict__ out,
               unsigned char* __restrict__ bp)
{
    __shared__ __align__(16) float sv[KK];
    const int b = blockIdx.x;
    const int lane = threadIdx.x;
    const float* emb = em + (size_t)b * TT * KK;
    unsigned char* bpb = bp + (size_t)b * TT * KK;
    int* outb = out + (size_t)b * TT;

    float tcol[KK];
#pragma unroll
    for (int i = 0; i < KK; ++i) tcol[i] = trans[i * KK + lane];
#pragma unroll
    for (int i = 0; i < KK; ++i) asm volatile("" : "+v"(tcol[i]));

    const int lenm1 = find_len(mask, b, lane) - 1;
    float score = emb[lane];
    sv[lane] = score;

    auto step = [&](float e, int tu) {
        const float4* svq = (const float4*)sv;
        float c[KK];
#pragma unroll
        for (int g = 0; g < 16; ++g) {
            float4 s4 = svq[g];
            c[4*g+0] = s4.x + tcol[4*g+0];
            c[4*g+1] = s4.y + tcol[4*g+1];
            c[4*g+2] = s4.z + tcol[4*g+2];
            c[4*g+3] = s4.w + tcol[4*g+3];
        }
        float m1[22];
#pragma unroll
        for (int g = 0; g < 21; ++g) m1[g] = max3f(c[3*g], c[3*g+1], c[3*g+2]);
        m1[21] = c[63];
        float m2[8];
#pragma unroll
        for (int g = 0; g < 7; ++g) m2[g] = max3f(m1[3*g], m1[3*g+1], m1[3*g+2]);
        m2[7] = m1[21];
        float best = max3f(max3f(m2[0], m2[1], m2[2]),
                           max3f(m2[3], m2[4], m2[5]), fmaxf(m2[6], m2[7]));
        score = best + e;
        sv[lane] = score;
        int bpi = 63;
#pragma unroll
        for (int i = KK - 2; i >= 0; --i) bpi = (c[i] == best) ? i : bpi;
        bpb[(size_t)tu * KK + lane] = (unsigned char)bpi;
    };

    float ebuf[4];
#pragma unroll
    for (int k = 0; k < 4; ++k) {
        int tp = 1 + k; if (tp > TT - 1) tp = TT - 1;
        ebuf[k] = emb[tp * KK + lane];
    }
    int t = 1;
#pragma unroll 1
    for (; t + 3 <= lenm1; t += 4) {
#pragma unroll
        for (int u = 0; u < 4; ++u) {
            float e = ebuf[u];
            int tp = t + 4 + u; if (tp > TT - 1) tp = TT - 1;
            ebuf[u] = emb[tp * KK + lane];
            step(e, t + u);
        }
    }
#pragma unroll 1
    for (; t <= lenm1; ++t) { float e = emb[t * KK + lane]; step(e, t); }

    float bv = score; int bi = lane;
#pragma unroll
    for (int off = 32; off; off >>= 1) {
        float ov = __shfl_xor(bv, off, 64);
        int oi = __shfl_xor(bi, off, 64);
        bool take = (ov > bv) || ((ov == bv) && (oi < bi));
        bv = take ? ov : bv;
        bi = take ? oi : bi;
    }
    int tag = __builtin_amdgcn_readfirstlane(bi);
    asm volatile("s_waitcnt vmcnt(0)" ::: "memory");

    const int cbase_top = lenm1 & ~63;
#pragma unroll 1
    for (int t0 = cbase_top + 64; t0 < TT; t0 += 64) outb[t0 + lane] = 0;

    const int rsub = lane >> 2;
    const int boff = (lane & 3) * 16;
    uint4 cur[4], nxt[4];
#pragma unroll
    for (int q = 0; q < 4; ++q)
        cur[q] = *(const uint4*)(bpb + (size_t)(cbase_top + 16 * q + rsub) * 64 + boff);
#pragma unroll
    for (int q = 0; q < 4; ++q) nxt[q] = cur[q];

    int stage = 0;
#pragma unroll 1
    for (int cbase = cbase_top; cbase >= 0; cbase -= 64) {
        if (cbase >= 64) {
#pragma unroll
            for (int q = 0; q < 4; ++q)
                nxt[q] = *(const uint4*)(bpb + (size_t)(cbase - 64 + 16 * q + rsub) * 64 + boff);
        }
#pragma unroll
        for (int s = 63; s >= 0; --s) {
            const int row = cbase + s;
            if (row <= lenm1) {
                stage = (lane == s) ? tag : stage;
                if (row >= 1) {
                    const int q = s >> 4;
                    const int lanei = ((s & 15) << 2) | (tag >> 4);
                    int w0 = __builtin_amdgcn_readlane((int)cur[q].x, lanei);
                    int w1 = __builtin_amdgcn_readlane((int)cur[q].y, lanei);
                    int w2 = __builtin_amdgcn_readlane((int)cur[q].z, lanei);
                    int w3 = __builtin_amdgcn_readlane((int)cur[q].w, lanei);
                    int a0 = (tag & 4) ? w1 : w0;
                    int a1 = (tag & 4) ? w3 : w2;
                    int word = (tag & 8) ? a1 : a0;
                    tag = (word >> ((tag & 3) * 8)) & 0xFF;
                }
            }
        }
        outb[cbase + lane] = stage;
        stage = 0;
#pragma unroll
        for (int q = 0; q < 4; ++q) cur[q] = nxt[q];
    }
}

extern "C" void kernel_launch(void* const* d_in, const int* in_sizes, int n_in,
                              void* d_out, int out_size, void* d_ws, size_t ws_size,
                              hipStream_t stream)
{
    const float* em    = (const float*)d_in[0];
    const int*   mask  = (const int*)d_in[1];
    const float* trans = (const float*)d_in[2];
    int* out = (int*)d_out;

    const size_t bpbytes = (size_t)BB * TT * KK;   // 16 MiB
    const size_t tagbytes = BB * sizeof(int);

    if (ws_size >= bpbytes + tagbytes) {
        unsigned char* bp = (unsigned char*)d_ws;
        int* last_tag = (int*)((char*)d_ws + bpbytes);
        vit_fwd_bp<<<dim3(BB), dim3(64), 0, stream>>>(em, mask, trans, bp, last_tag);
        vit_bt<<<dim3(BB), dim3(64), 0, stream>>>(mask, bp, last_tag, out);
    } else {
        viterbi64<<<dim3(BB), dim3(64), 0, stream>>>(em, mask, trans, out,
                                                     (unsigned char*)d_ws);
    }
}